// Round 7
// baseline (6919.020 us; speedup 1.0000x reference)
//
#include <hip/hip_runtime.h>
#include <stdint.h>

// ---------------------------------------------------------------------------
// TreeLSTMParser: N=2048 nodes/timesteps, D_IN=H=768, OUT=128.
// Tree: complete binary tree, parent(i)=(i-1)/2; level L = [2^(10-L),2^(11-L))
// for L=1..10, level 0 = leaves [1024,2048), level 11 = {0}.
//
// Inputs fp32 (detector-confirmed r3).  All tensors canonicalized to bf16.
//
// seq_lstm v5: packed-dot compute + 32wg x 768thr + single barrier.
// r6 post-mortem: VALUBusy 5.7% x (256/24 CUs) ~= 61% on active CUs -> the
// bottleneck moved to VALU issue (192 instr/thread for 96 MACs with manual
// bf16 unpack).  v5 stages h as packed bf16 pairs and uses v_dot2_f32_bf16
// (2 MAC/instr, no unpack): 48 instr/thread.  LDS parity double-buffer
// removes the trailing barrier (provably safe: reaching stage(t+2) requires
// passing barrier(t+1), which implies all threads finished compute(t)).
// ---------------------------------------------------------------------------

typedef __bf16 bf16x8 __attribute__((ext_vector_type(8)));
typedef float  f32x4  __attribute__((ext_vector_type(4)));
typedef unsigned long long u64;
typedef __bf16 bf16x2 __attribute__((ext_vector_type(2)));
typedef _Float16 half2v __attribute__((ext_vector_type(2)));

#if __has_builtin(__builtin_amdgcn_fdot2_f32_bf16)
  #define DOT_MODE 2
#elif __has_builtin(__builtin_amdgcn_fdot2)
  #define DOT_MODE 1
#else
  #define DOT_MODE 0
#endif

__device__ __forceinline__ float bf2f(uint16_t v) {
    return __uint_as_float(((uint32_t)v) << 16);
}
__device__ __forceinline__ uint16_t f2bf(float f) {
    uint32_t u = __float_as_uint(f);
    uint32_t r = (u + 0x7fffu + ((u >> 16) & 1u)) >> 16;
    return (uint16_t)r;
}
__device__ __forceinline__ float sigf(float x) { return 1.0f / (1.0f + __expf(-x)); }
__device__ __forceinline__ float tanh_f(float x) {
    x = fminf(fmaxf(x, -15.0f), 15.0f);
    float e = __expf(2.0f * x);
    return (e - 1.0f) / (e + 1.0f);
}
__device__ __forceinline__ float dot8(uint4 w, const float* h, float acc) {
    acc = fmaf(__uint_as_float(w.x << 16),          h[0], acc);
    acc = fmaf(__uint_as_float(w.x & 0xffff0000u),  h[1], acc);
    acc = fmaf(__uint_as_float(w.y << 16),          h[2], acc);
    acc = fmaf(__uint_as_float(w.y & 0xffff0000u),  h[3], acc);
    acc = fmaf(__uint_as_float(w.z << 16),          h[4], acc);
    acc = fmaf(__uint_as_float(w.z & 0xffff0000u),  h[5], acc);
    acc = fmaf(__uint_as_float(w.w << 16),          h[6], acc);
    acc = fmaf(__uint_as_float(w.w & 0xffff0000u),  h[7], acc);
    return acc;
}

// --- packed-pair helpers for seq_lstm --------------------------------------
__device__ __forceinline__ float dotpair(uint32_t w, uint32_t h, float acc) {
#if DOT_MODE == 2
    return __builtin_amdgcn_fdot2_f32_bf16(__builtin_bit_cast(bf16x2, w),
                                           __builtin_bit_cast(bf16x2, h),
                                           acc, false);
#elif DOT_MODE == 1
    return __builtin_amdgcn_fdot2(__builtin_bit_cast(half2v, w),
                                  __builtin_bit_cast(half2v, h),
                                  acc, false);
#else
    float a1 = fmaf(__uint_as_float(w << 16), __uint_as_float(h << 16), acc);
    return fmaf(__uint_as_float(w & 0xffff0000u),
                __uint_as_float(h & 0xffff0000u), a1);
#endif
}
__device__ __forceinline__ uint32_t prepw(uint32_t u) {   // bf16 pair -> dot fmt
#if DOT_MODE == 1
    float lo = __uint_as_float(u << 16);
    float hi = __uint_as_float(u & 0xffff0000u);
    half2v h = {(_Float16)lo, (_Float16)hi};
    return __builtin_bit_cast(uint32_t, h);
#else
    return u;
#endif
}
__device__ __forceinline__ uint16_t preph(float f) {      // f32 -> dot halfword
#if DOT_MODE == 1
    _Float16 h = (_Float16)f;
    return __builtin_bit_cast(uint16_t, h);
#else
    return f2bf(f);
#endif
}

// ---------------------------------------------------------------------------
// K0a: dtype detector (fp32 read as bf16 halfwords shows exponent==0xFF).
// ---------------------------------------------------------------------------
__global__ __launch_bounds__(256)
void detect_mode(const uint16_t* __restrict__ p, int* __restrict__ mode)
{
    int i = blockIdx.x * 256 + threadIdx.x;
    uint16_t v = p[i];
    bool bad = ((v >> 7) & 0xFF) == 0xFF;
    if (__ballot(bad) != 0ull) {
        if ((threadIdx.x & 63) == 0) atomicOr(mode, 1);
    }
}

// ---------------------------------------------------------------------------
// K0b: canonicalize all tensors to bf16 (copy or downcast per mode).
// ---------------------------------------------------------------------------
struct ConvArgs {
    const void* src[14];
    void*       dst[14];
    int         n[14];
};

__global__ __launch_bounds__(256)
void conv_canon(ConvArgs a, const int* __restrict__ mode)
{
    int t = blockIdx.y;
    int n = a.n[t];
    int i = (blockIdx.x * 256 + threadIdx.x) * 8;
    if (i >= n) return;
    uint16_t* d = (uint16_t*)a.dst[t] + i;
    if (*mode) {
        const float* s = (const float*)a.src[t] + i;
        float4 v0 = reinterpret_cast<const float4*>(s)[0];
        float4 v1 = reinterpret_cast<const float4*>(s)[1];
        d[0] = f2bf(v0.x); d[1] = f2bf(v0.y); d[2] = f2bf(v0.z); d[3] = f2bf(v0.w);
        d[4] = f2bf(v1.x); d[5] = f2bf(v1.y); d[6] = f2bf(v1.z); d[7] = f2bf(v1.w);
    } else {
        *reinterpret_cast<uint4*>(d) =
            *reinterpret_cast<const uint4*>((const uint16_t*)a.src[t] + i);
    }
}

// ---------------------------------------------------------------------------
// K1: fused projection GEMM.  C(2048 x 6144) = A @ W^T + bias, K=768.
// seq region written PERMUTED for 24-wide wg ownership (32 wgs):
//   idx = (j/24)*96 + g*24 + (j%24)
// ---------------------------------------------------------------------------
__global__ __launch_bounds__(256)
void gemm_pre(const uint16_t* __restrict__ treeF, const uint16_t* __restrict__ featF,
              const uint16_t* __restrict__ W_iou, const uint16_t* __restrict__ b_iou,
              const uint16_t* __restrict__ W_f,   const uint16_t* __restrict__ b_f,
              const uint16_t* __restrict__ W_ih,  const uint16_t* __restrict__ b_ih,
              const uint16_t* __restrict__ b_hh,
              uint16_t* __restrict__ x_iou, uint16_t* __restrict__ x_f,
              uint16_t* __restrict__ seq_pre)
{
    int lane = threadIdx.x & 63;
    int wave = threadIdx.x >> 6;
    int colTile = blockIdx.x * 4 + wave;     // 0..383
    int row0 = blockIdx.y * 16;              // 0..2032
    int cl = lane & 15, quad = lane >> 4;
    int colg = colTile * 16;

    const uint16_t* A; const uint16_t* W; int wrow;
    if (colTile < 144)      { A = treeF; W = W_iou; wrow = colg; }
    else if (colTile < 192) { A = treeF; W = W_f;   wrow = colg - 2304; }
    else                    { A = featF; W = W_ih;  wrow = colg - 3072; }

    const uint16_t* arow = A + (size_t)(row0 + cl) * 768 + quad * 8;
    const uint16_t* brow = W + (size_t)(wrow + cl) * 768 + quad * 8;

    f32x4 acc = {0.f, 0.f, 0.f, 0.f};
    for (int k = 0; k < 768; k += 32) {
        bf16x8 a = *reinterpret_cast<const bf16x8*>(arow + k);
        bf16x8 b = *reinterpret_cast<const bf16x8*>(brow + k);
        acc = __builtin_amdgcn_mfma_f32_16x16x32_bf16(a, b, acc, 0, 0, 0);
    }

    // C/D layout: col = lane&15, row = quad*4 + reg   [m89-verified]
    int outcol = colg + cl;
    float bias; uint16_t* dst; int ldc; int ccol;
    if (colTile < 144)      { bias = bf2f(b_iou[outcol]); dst = x_iou; ldc = 2304; ccol = outcol; }
    else if (colTile < 192) { int c = outcol - 2304; bias = bf2f(b_f[c]); dst = x_f; ldc = 768;  ccol = c; }
    else {
        int c = outcol - 3072;               // c = g*768 + j
        int g = c / 768, j = c - g * 768;
        bias = bf2f(b_ih[c]) + bf2f(b_hh[c]);
        dst = seq_pre; ldc = 3072;
        int wgIdx = j / 24, within = j - wgIdx * 24;
        ccol = wgIdx * 96 + g * 24 + within;     // permuted
    }
    for (int r = 0; r < 4; ++r) {
        int row = row0 + quad * 4 + r;
        dst[(size_t)row * ldc + ccol] = f2bf(acc[r] + bias);
    }
}

// ---------------------------------------------------------------------------
// K2a: per-level dot products (tree).
// ---------------------------------------------------------------------------
__global__ __launch_bounds__(256)
void tree_dots(int s, int m,
               const uint16_t* __restrict__ U_iou, const uint16_t* __restrict__ U_f,
               const uint16_t* __restrict__ x_f,
               uint16_t* __restrict__ x_iou, uint16_t* __restrict__ fdot,
               const float* __restrict__ tree_h)
{
    int id = blockIdx.x * 256 + threadIdx.x;
    int niou = m * 2304;
    if (id < niou) {
        int pl = id / 2304;
        int j = id - pl * 2304;
        int p = s + pl;
        int c1 = 2 * p + 1, c2 = 2 * p + 2;
        const uint16_t* urow = U_iou + (size_t)j * 768;
        const float* h1 = tree_h + (size_t)c1 * 768;
        float acc = 0.f;
        if (c2 < 2048) {
            const float* h2 = tree_h + (size_t)c2 * 768;
            for (int k = 0; k < 768; k += 8) {
                uint4 w = *reinterpret_cast<const uint4*>(urow + k);
                float hsum[8];
                #pragma unroll
                for (int i = 0; i < 8; ++i) hsum[i] = h1[k + i] + h2[k + i];
                acc = dot8(w, hsum, acc);
            }
        } else {
            for (int k = 0; k < 768; k += 8) {
                uint4 w = *reinterpret_cast<const uint4*>(urow + k);
                acc = dot8(w, h1 + k, acc);
            }
        }
        size_t off = (size_t)p * 2304 + j;
        x_iou[off] = f2bf(bf2f(x_iou[off]) + acc);
    } else {
        int e = id - niou;                 // < m*1536
        int eid = e / 768;
        int j = e - eid * 768;
        int p = s + (eid >> 1);
        int c = 2 * p + 1 + (eid & 1);
        if (c >= 2048) return;             // node 1023 has one child
        const uint16_t* urow = U_f + (size_t)j * 768;
        const float* hc = tree_h + (size_t)c * 768;
        float acc = 0.f;
        for (int k = 0; k < 768; k += 8) {
            uint4 w = *reinterpret_cast<const uint4*>(urow + k);
            acc = dot8(w, hc + k, acc);
        }
        fdot[(size_t)c * 768 + j] = f2bf(bf2f(x_f[(size_t)p * 768 + j]) + acc);
    }
}

// ---------------------------------------------------------------------------
// K2b: per-level combine (tree).
// ---------------------------------------------------------------------------
__global__ __launch_bounds__(256)
void tree_combine(int s, int m, const uint16_t* __restrict__ x_iou,
                  const uint16_t* __restrict__ fdot,
                  float* __restrict__ tree_h, float* __restrict__ tree_c)
{
    int id = blockIdx.x * 256 + threadIdx.x;
    int pl = id / 768;
    int j = id - pl * 768;
    int p = s + pl;
    const uint16_t* iou = x_iou + (size_t)p * 2304;
    float iv = sigf(bf2f(iou[j]));
    float ov = sigf(bf2f(iou[768 + j]));
    float uv = tanh_f(bf2f(iou[1536 + j]));
    float csum = 0.f;
    int c1 = 2 * p + 1, c2 = 2 * p + 2;
    if (c1 < 2048) csum += sigf(bf2f(fdot[(size_t)c1 * 768 + j])) * tree_c[(size_t)c1 * 768 + j];
    if (c2 < 2048) csum += sigf(bf2f(fdot[(size_t)c2 * 768 + j])) * tree_c[(size_t)c2 * 768 + j];
    float c = iv * uv + csum;
    tree_c[(size_t)p * 768 + j] = c;
    tree_h[(size_t)p * 768 + j] = ov * tanh_f(c);
}

// ---------------------------------------------------------------------------
// K3 v5: persistent sequential LSTM.  32 wgs x 768 threads.
// Thread (jl=tid>>5 in 0..23, g=(tid>>3)&3, p=tid&7) holds W_hh row
// g*768 + (j0+jl), cols [p*96,p*96+96) as 48 packed pairs (j0 = bid*24).
// h_comm: 2 parity x 768 u64; word = (tag=t+1)<<32 | f32(h).
// Per step: each thread polls ONE u64 (tag>=t), converts to packed halfword
// in LDS (parity buffer, part stride 52 dwords: 16B-aligned b128 reads,
// banks 20p%32 distinct); ONE barrier; 48 dot2 instr; shfl reduce/gather;
// gate math; 24 publishers store u64.  No trailing barrier (parity-safe).
// ---------------------------------------------------------------------------
#define SEQ_G 32
__global__ __launch_bounds__(768)
void seq_lstm(const uint16_t* __restrict__ W_hh, const uint16_t* __restrict__ seq_pre,
              float* __restrict__ hs, u64* __restrict__ h_comm)
{
    __shared__ uint32_t hp2[2 * 416];   // parity x (8 parts x 52 dwords)

    int tid = threadIdx.x;
    int bid = blockIdx.x;           // 0..31
    int j0 = bid * 24;
    int lane = tid & 63;
    int jl = tid >> 5;              // 0..23
    int g  = (tid >> 3) & 3;        // gate
    int p  = tid & 7;               // K-part
    int j  = j0 + jl;               // owned h index
    int row = g * 768 + j;          // W_hh row

    // weights: 48 packed pairs = cols [p*96, p*96+96) of row
    uint32_t wq[48];
    {
        const uint16_t* srcw = W_hh + (size_t)row * 768 + p * 96;
        #pragma unroll
        for (int i = 0; i < 12; ++i) {
            uint4 v = *reinterpret_cast<const uint4*>(srcw + i * 8);
            wq[4*i+0] = prepw(v.x); wq[4*i+1] = prepw(v.y);
            wq[4*i+2] = prepw(v.z); wq[4*i+3] = prepw(v.w);
        }
    }

    // permuted seq_pre offset (wg reads contiguous 96 bf16 per step)
    int preOff = bid * 96 + g * 24 + jl;

    // staging map: thread stages h word w=tid -> part sp, col sc
    int sp = tid / 96;
    int sc = tid - sp * 96;
    int hIdx = (sp * 52 + (sc >> 1)) * 2 + (sc & 1);   // halfword idx in parity buf

    float cstate = 0.f;

    for (int t = 0; t < 2048; ++t) {
        float pre = bf2f(seq_pre[(size_t)t * 3072 + preOff]);  // prefetch

        if (t > 0) {
            const u64* hw = h_comm + (size_t)((t - 1) & 1) * 768 + tid;
            u64 a;
            int guard = 0;
            for (;;) {
                a = __hip_atomic_load(hw, __ATOMIC_RELAXED,
                                      __HIP_MEMORY_SCOPE_AGENT);
                if ((uint32_t)(a >> 32) >= (uint32_t)t) break;
                if (++guard > (1 << 22)) break;      // hang bailout
                __builtin_amdgcn_s_sleep(1);
            }
            reinterpret_cast<uint16_t*>(hp2)[(t & 1) * 832 + hIdx] =
                preph(__uint_as_float((uint32_t)a));
        } else {
            if (tid < 416) hp2[tid] = 0;             // zero parity 0
        }
        __syncthreads();

        // dot: 12 x b128 LDS reads, 48 packed dot2
        const uint4* hq = reinterpret_cast<const uint4*>(
            hp2 + (t & 1) * 416 + p * 52);
        float acc = 0.f;
        #pragma unroll
        for (int i = 0; i < 12; ++i) {
            uint4 hv = hq[i];
            acc = dotpair(wq[4*i+0], hv.x, acc);
            acc = dotpair(wq[4*i+1], hv.y, acc);
            acc = dotpair(wq[4*i+2], hv.z, acc);
            acc = dotpair(wq[4*i+3], hv.w, acc);
        }

        // butterfly-reduce over p (lane bits 0..2)
        acc += __shfl_xor(acc, 1);
        acc += __shfl_xor(acc, 2);
        acc += __shfl_xor(acc, 4);
        float gate = acc + pre;                  // uniform across 8-lane group

        // gather the 4 gates of this half-wave's j
        int base = lane & 32;
        float gi = __shfl(gate, base);
        float gf = __shfl(gate, base + 8);
        float gg = __shfl(gate, base + 16);
        float go = __shfl(gate, base + 24);

        float iv = sigf(gi), fv = sigf(gf), gv = tanh_f(gg), ov = sigf(go);
        cstate = fv * cstate + iv * gv;          // replicated per 32-thread group
        float hv2 = ov * tanh_f(cstate);

        // publish: tag travels with data — single relaxed sc1 u64 store
        if ((tid & 31) == 0) {                   // g==0 && p==0, one per jl
            u64 wd = ((u64)(uint32_t)(t + 1) << 32) | (u64)__float_as_uint(hv2);
            __hip_atomic_store(h_comm + (size_t)(t & 1) * 768 + j, wd,
                               __ATOMIC_RELAXED, __HIP_MEMORY_SCOPE_AGENT);
            hs[(size_t)t * 768 + j] = hv2;       // off critical path (fp32)
        }
        // no trailing barrier: LDS parity double-buffer protects reads
    }
}

// ---------------------------------------------------------------------------
// K4: classifier logits[n][o] = b_cls[o] + [tree_h[n] | hs[n]] . W_cls[o]
// ---------------------------------------------------------------------------
__global__ __launch_bounds__(128)
void cls_logits(const float* __restrict__ tree_h, const float* __restrict__ hs,
                const uint16_t* __restrict__ W_cls, const uint16_t* __restrict__ b_cls,
                float* __restrict__ logits)
{
    __shared__ float cin[1536];
    int n = blockIdx.x, tid = threadIdx.x;
    for (int k = tid; k < 768; k += 128) {
        cin[k]       = tree_h[(size_t)n * 768 + k];
        cin[768 + k] = hs[(size_t)n * 768 + k];
    }
    __syncthreads();
    const uint16_t* wrow = W_cls + (size_t)tid * 1536;
    float acc = bf2f(b_cls[tid]);
    for (int k = 0; k < 1536; k += 8) {
        uint4 w = *reinterpret_cast<const uint4*>(wrow + k);
        acc = dot8(w, cin + k, acc);
    }
    logits[(size_t)n * 128 + tid] = acc;
}

// ---------------------------------------------------------------------------
// K5: log_softmax over axis=0 per class column.  Output dtype per mode.
// ---------------------------------------------------------------------------
__global__ __launch_bounds__(256)
void col_softmax(const float* __restrict__ logits, void* __restrict__ out,
                 const int* __restrict__ mode)
{
    __shared__ float sred[256];
    int o = blockIdx.x, tid = threadIdx.x;
    float v[8];
    float mx = -1e30f;
    #pragma unroll
    for (int i = 0; i < 8; ++i) {
        v[i] = logits[(size_t)(i * 256 + tid) * 128 + o];
        mx = fmaxf(mx, v[i]);
    }
    sred[tid] = mx; __syncthreads();
    for (int s2 = 128; s2 > 0; s2 >>= 1) {
        if (tid < s2) sred[tid] = fmaxf(sred[tid], sred[tid + s2]);
        __syncthreads();
    }
    float M = sred[0]; __syncthreads();
    float sm = 0.f;
    #pragma unroll
    for (int i = 0; i < 8; ++i) sm += __expf(v[i] - M);
    sred[tid] = sm; __syncthreads();
    for (int s2 = 128; s2 > 0; s2 >>= 1) {
        if (tid < s2) sred[tid] += sred[tid + s2];
        __syncthreads();
    }
    float lse = M + logf(sred[0]);
    bool fp32 = (*mode != 0);
    #pragma unroll
    for (int i = 0; i < 8; ++i) {
        size_t idx = (size_t)(i * 256 + tid) * 128 + o;
        float val = v[i] - lse;
        if (fp32) ((float*)out)[idx] = val;
        else      ((uint16_t*)out)[idx] = f2bf(val);
    }
}

// ---------------------------------------------------------------------------
extern "C" void kernel_launch(void* const* d_in, const int* in_sizes, int n_in,
                              void* d_out, int out_size, void* d_ws, size_t ws_size,
                              hipStream_t stream)
{
    char* ws = (char*)d_ws;

    // ---- canonical bf16 tensor area (element offsets) ----
    static const int   CN[14] = {1572864, 1572864, 1769472, 1769472, 589824, 589824,
                                 2359296, 2359296, 196608, 2304, 768, 3072, 3072, 128};
    static const size_t COFF[14] = {0, 1572864, 3145728, 4915200, 6684672, 7274496,
                                    7864320, 10223616, 12582912, 12779520, 12781824,
                                    12782592, 12785664, 12788736};
    // canon slots: 0 treeF(d_in 0), 1 featF(1), 2 W_iou(2), 3 U_iou(4), 4 W_f(5),
    //              5 U_f(7), 6 W_ih(8), 7 W_hh(10), 8 W_cls(12), 9 b_iou(3),
    //              10 b_f(6), 11 b_ih(9), 12 b_hh(11), 13 b_cls(13)
    static const int SRCI[14] = {0, 1, 2, 4, 5, 7, 8, 10, 12, 3, 6, 9, 11, 13};

    uint16_t* canon = (uint16_t*)ws;
    const uint16_t* treeF = canon + COFF[0];
    const uint16_t* featF = canon + COFF[1];
    const uint16_t* W_iou = canon + COFF[2];
    const uint16_t* U_iou = canon + COFF[3];
    const uint16_t* W_f   = canon + COFF[4];
    const uint16_t* U_f   = canon + COFF[5];
    const uint16_t* W_ih  = canon + COFF[6];
    const uint16_t* W_hh  = canon + COFF[7];
    const uint16_t* W_cls = canon + COFF[8];
    const uint16_t* b_iou = canon + COFF[9];
    const uint16_t* b_f   = canon + COFF[10];
    const uint16_t* b_ih  = canon + COFF[11];
    const uint16_t* b_hh  = canon + COFF[12];
    const uint16_t* b_cls = canon + COFF[13];

    const size_t CANON_B = 25577728;                  // 12788864 el * 2
    uint16_t* x_iou   = (uint16_t*)(ws + CANON_B);            //  9437184 B
    uint16_t* seq_pre = (uint16_t*)(ws + CANON_B + 9437184);  // 12582912 B
    uint16_t* x_f     = (uint16_t*)(ws + CANON_B + 22020096); //  3145728 B
    uint16_t* fdot    = (uint16_t*)(ws + CANON_B + 25165824); //  3145728 B
    float*    tree_h  = (float*)   (ws + CANON_B + 28311552); //  6291456 B
    float*    tree_c  = (float*)   (ws + CANON_B + 34603008); //  6291456 B
    float*    hs      = (float*)   (ws + CANON_B + 40894464); //  6291456 B
    float*    logits  = (float*)   (ws + CANON_B + 47185920); //  1048576 B
    u64*      h_comm  = (u64*)     (ws + CANON_B + 48234496); //    12288 B (2x768 u64)
    int*      mode    = (int*)     (ws + CANON_B + 48246784); //      256 B
    const size_t WS_NEEDED = CANON_B + 48247040;              // ~70.4 MB
    if (ws_size < WS_NEEDED) return;  // diagnostic: out stays 0 (absmax ~8.56)

    hipMemsetAsync(h_comm, 0, 12288 + 256, stream);   // tags + mode

    detect_mode<<<256, 256, 0, stream>>>((const uint16_t*)d_in[0], mode);

    ConvArgs ca;
    for (int i = 0; i < 14; ++i) {
        ca.src[i] = d_in[SRCI[i]];
        ca.dst[i] = canon + COFF[i];
        ca.n[i]   = CN[i];
    }
    conv_canon<<<dim3(1152, 14), 256, 0, stream>>>(ca, mode);

    gemm_pre<<<dim3(96, 128), 256, 0, stream>>>(treeF, featF, W_iou, b_iou, W_f, b_f,
                                                W_ih, b_ih, b_hh, x_iou, x_f, seq_pre);

    // level 0 (leaves 1024..2047): combine only
    tree_combine<<<1024 * 3, 256, 0, stream>>>(1024, 1024, x_iou, fdot, tree_h, tree_c);
    for (int lvl = 1; lvl <= 11; ++lvl) {
        int s = (lvl == 11) ? 0 : (1 << (10 - lvl));
        int m = (lvl == 11) ? 1 : (1 << (10 - lvl));
        tree_dots<<<m * 15, 256, 0, stream>>>(s, m, U_iou, U_f, x_f, x_iou, fdot, tree_h);
        tree_combine<<<m * 3, 256, 0, stream>>>(s, m, x_iou, fdot, tree_h, tree_c);
    }

    seq_lstm<<<SEQ_G, 768, 0, stream>>>(W_hh, seq_pre, hs, h_comm);

    cls_logits<<<2048, 128, 0, stream>>>(tree_h, hs, W_cls, b_cls, logits);
    col_softmax<<<128, 256, 0, stream>>>(logits, d_out, mode);
}